// Round 1
// baseline (48.462 us; speedup 1.0000x reference)
//
#include <hip/hip_runtime.h>

// buckets = perm[ packbits( mat[b,h,n,:] @ proj[:,r] > 0 ) ]
// mat: [2,32,8192,64] f32   proj: [64,8] f32   perm: [256] i32   out: [2*32*8192] i32

constexpr int ROWS = 2 * 32 * 8192;   // 524288
constexpr int D = 64;
constexpr int R = 8;

__global__ __launch_bounds__(256) void lsh_kernel(
    const float* __restrict__ mat,
    const float* __restrict__ proj,
    const int*   __restrict__ perm,
    int*         __restrict__ out)
{
    const int tid = blockIdx.x * 256 + threadIdx.x;  // one row per thread
    const float4* row = reinterpret_cast<const float4*>(mat) + (size_t)tid * (D / 4);

    float s[R] = {0.f, 0.f, 0.f, 0.f, 0.f, 0.f, 0.f, 0.f};

    #pragma unroll
    for (int k = 0; k < D / 4; ++k) {
        float4 v = row[k];
        float vv[4] = {v.x, v.y, v.z, v.w};
        #pragma unroll
        for (int j = 0; j < 4; ++j) {
            const int d = k * 4 + j;
            #pragma unroll
            for (int r = 0; r < R; ++r) {
                s[r] = fmaf(vv[j], proj[d * R + r], s[r]);
            }
        }
    }

    int bin = 0;
    #pragma unroll
    for (int r = 0; r < R; ++r) {
        bin |= (s[r] > 0.0f) ? (1 << r) : 0;
    }

    out[tid] = perm[bin];
}

extern "C" void kernel_launch(void* const* d_in, const int* in_sizes, int n_in,
                              void* d_out, int out_size, void* d_ws, size_t ws_size,
                              hipStream_t stream) {
    const float* mat  = (const float*)d_in[0];   // [2,32,8192,64] f32
    const float* proj = (const float*)d_in[1];   // [1,1,64,8] f32
    const int*   perm = (const int*)d_in[2];     // [256] i32
    // d_in[3] = enc_vec, implicit in the bit-packing order
    int* out = (int*)d_out;                      // [524288] i32

    lsh_kernel<<<ROWS / 256, 256, 0, stream>>>(mat, proj, perm, out);
}

// Round 2
// 39.599 us; speedup vs baseline: 1.2238x; 1.2238x over previous
//
#include <hip/hip_runtime.h>

// buckets = perm[ packbits( mat[row,:] @ proj[:,r] > 0 ) ]
// mat: [2,32,8192,64] f32   proj: [64,8] f32   perm: [256] i32   out: [524288] i32
//
// Layout: one row per lane. Each wave stages its own 64 rows (16 KiB) into a
// private LDS slice via global_load_lds (width 16). Because global_load_lds
// writes LDS linearly (wave-uniform base + lane*16), the bank-conflict swizzle
// is applied to the per-lane GLOBAL source address (chunk k of row r lands at
// float4-slot k ^ (r&7)); the read side applies the same XOR. proj index stays
// wave-uniform -> SGPR operand in the FMAs.

constexpr int ROWS = 2 * 32 * 8192;   // 524288
constexpr int D = 64;
constexpr int R = 8;

__global__ __launch_bounds__(256) void lsh_kernel(
    const float* __restrict__ mat,
    const float* __restrict__ proj,
    const int*   __restrict__ perm,
    int*         __restrict__ out)
{
    __shared__ float lds[256 * D];                 // 64 KiB: 4 waves x 64 rows x 64 f32
    const int lane = threadIdx.x & 63;
    const int wid  = threadIdx.x >> 6;
    const int waveRowBase = blockIdx.x * 256 + wid * 64;

    float* ldsWave = &lds[wid * (64 * D)];

    // ---- stage: 16 x global_load_lds_dwordx4, each fills 1 KiB (4 rows) ----
    // dest float4-slot s = i*64 + lane; row-local rl = s>>4; dest chunk kd = s&15.
    // content stored there = global chunk ks = kd ^ (rl & 7)  (XOR is an involution)
    #pragma unroll
    for (int i = 0; i < 16; ++i) {
        const int rl = i * 4 + (lane >> 4);
        const int ks = (lane & 15) ^ (rl & 7);
        const float* src = mat + ((size_t)(waveRowBase + rl) * D + ks * 4);
        __builtin_amdgcn_global_load_lds(
            (const __attribute__((address_space(1))) void*)src,
            (__attribute__((address_space(3))) void*)(ldsWave + i * 256),
            16, 0, 0);
    }
    asm volatile("s_waitcnt vmcnt(0)" ::: "memory");   // wave-private slice: no barrier needed

    // ---- compute: one row per lane, swizzled readback ----
    float s[R] = {0.f, 0.f, 0.f, 0.f, 0.f, 0.f, 0.f, 0.f};
    #pragma unroll
    for (int k = 0; k < 16; ++k) {
        const int slot = lane * 16 + (k ^ (lane & 7));          // float4 slot
        const float4 v = *reinterpret_cast<const float4*>(&ldsWave[slot * 4]);
        const float vv[4] = {v.x, v.y, v.z, v.w};
        #pragma unroll
        for (int j = 0; j < 4; ++j) {
            const int d = k * 4 + j;
            #pragma unroll
            for (int r = 0; r < R; ++r)
                s[r] = fmaf(vv[j], proj[d * R + r], s[r]);      // proj: SGPR operand
        }
    }

    int bin = 0;
    #pragma unroll
    for (int r = 0; r < R; ++r)
        bin |= (s[r] > 0.0f) ? (1 << r) : 0;

    out[waveRowBase + lane] = perm[bin];
}

extern "C" void kernel_launch(void* const* d_in, const int* in_sizes, int n_in,
                              void* d_out, int out_size, void* d_ws, size_t ws_size,
                              hipStream_t stream) {
    const float* mat  = (const float*)d_in[0];   // [2,32,8192,64] f32
    const float* proj = (const float*)d_in[1];   // [1,1,64,8] f32
    const int*   perm = (const int*)d_in[2];     // [256] i32
    // d_in[3] = enc_vec, implicit in the bit-packing order
    int* out = (int*)d_out;                      // [524288] i32

    lsh_kernel<<<ROWS / 256, 256, 0, stream>>>(mat, proj, perm, out);
}